// Round 10
// baseline (144.426 us; speedup 1.0000x reference)
//
#include <hip/hip_runtime.h>

// MHA fused forward: B=2,S=2048,D=1024,H=16,DK=64, causal, scores *= 8.
// Pipeline: cvt(fp32->fp16) -> 3x proj GEMM (fused, grid.z) -> flash attn -> out GEMM.
// Attn: 32x32x16 MFMA, swapped QK^T (S^T = K*Q^T), softmax in-register via
// permlane32_swap builtin, P packed (cvt_pkrtz+permlane) into PV B-fragment,
// O^T = V^T*P with lane-local rescale.
// R10: kill idle wave-slots. Previously block = strips {p, 63-p}: the short wave
// idled ~half the block's iterations (52% slot utilization). Now both waves own
// the SAME 64-row q-tile (rows qt*64 + w*32 ..+32) -> identical kv trip counts
// (0..qt), zero idle slots. LPT dispatch (qt = 31-rank) + backfill balances blocks.

typedef float f32x4 __attribute__((ext_vector_type(4)));
typedef float f32x16 __attribute__((ext_vector_type(16)));
typedef unsigned int u32x4 __attribute__((ext_vector_type(4)));
typedef _Float16 f16x8 __attribute__((ext_vector_type(8)));
typedef __fp16 fp16x2 __attribute__((ext_vector_type(2)));

#define DEV static __device__ __forceinline__

DEV unsigned short f2h(float x) {
  _Float16 h = (_Float16)x;
  union { _Float16 h; unsigned short u; } v; v.h = h;
  return v.u;
}

DEV unsigned pkrtz(float a, float b) {
  union { fp16x2 h; unsigned u; } v;
  v.h = __builtin_amdgcn_cvt_pkrtz(a, b);
  return v.u;
}

// permlane32_swap builtin: lanes 0-31 of b' get a's lanes 32-63 and vice versa.
DEV void pswap(unsigned& a, unsigned& b) {
  auto r = __builtin_amdgcn_permlane32_swap(a, b, false, false);
  a = r[0]; b = r[1];
}

// Give every lane the {own, partner(lane^32)} pair of v in (x, y).
DEV void swap_pair(float v, float& x, float& y) {
  union { float f; unsigned u; } in; in.f = v;
  auto r = __builtin_amdgcn_permlane32_swap(in.u, in.u, false, false);
  union { unsigned u; float f; } ox, oy; ox.u = r[0]; oy.u = r[1];
  x = ox.f; y = oy.f;
}

DEV f16x8 mkfrag(unsigned a, unsigned b, unsigned c, unsigned d) {
  union { unsigned u[4]; f16x8 v; } z;
  z.u[0] = a; z.u[1] = b; z.u[2] = c; z.u[3] = d;
  return z.v;
}

DEV void mfma16(f32x4& d, u32x4 a, u32x4 b) {
  asm("v_mfma_f32_16x16x32_f16 %0, %1, %2, %0" : "+v"(d) : "v"(a), "v"(b));
}

DEV void gload16(const void* g, void* l) {
  __builtin_amdgcn_global_load_lds(
      (const __attribute__((address_space(1))) unsigned int*)g,
      (__attribute__((address_space(3))) unsigned int*)l, 16, 0, 0);
}

#define VMCNT0() asm volatile("s_waitcnt vmcnt(0)" ::: "memory")
#define NOPG(a,b,c,d)  asm volatile("s_nop 7\n\ts_nop 7" : "+v"(a), "+v"(b), "+v"(c), "+v"(d))

// ---------------- fp32 -> fp16 convert (k,q,v,wk,wq,wv,wo), 16.78M elements ----
__global__ __launch_bounds__(256) void cvt_all(
    const float* __restrict__ k, const float* __restrict__ q, const float* __restrict__ v,
    const float* __restrict__ wk, const float* __restrict__ wq, const float* __restrict__ wv,
    const float* __restrict__ wo, unsigned short* __restrict__ dst) {
  const int i = (blockIdx.x * 256 + threadIdx.x) * 4;
  const float* src; int off;
  if (i < 4194304)       { src = k;  off = 0; }
  else if (i < 8388608)  { src = q;  off = 4194304; }
  else if (i < 12582912) { src = v;  off = 8388608; }
  else if (i < 13631488) { src = wk; off = 12582912; }
  else if (i < 14680064) { src = wq; off = 13631488; }
  else if (i < 15728640) { src = wv; off = 14680064; }
  else                   { src = wo; off = 15728640; }
  float4 val = *(const float4*)(src + (i - off));
  ushort4 o;
  o.x = f2h(val.x); o.y = f2h(val.y); o.z = f2h(val.z); o.w = f2h(val.w);
  *(ushort4*)(dst + i) = o;
}

// ---------------- NT GEMM 128x128 tile, BK=32, M=4096,N=1024,K=1024 -----------
DEV void gemm_body(const unsigned short* __restrict__ A, const unsigned short* __restrict__ W,
                   const float* __restrict__ bias, void* __restrict__ out, int mode,
                   float oscale) {
  __shared__ alignas(16) char lds_a[2][8192];
  __shared__ alignas(16) char lds_b[2][8192];
  const int t = threadIdx.x;
  const int l = t & 63, g = l >> 4, c = l & 15, w = t >> 6;
  const int wr = w >> 1, wc = w & 1;
  const int m0 = blockIdx.y << 7, n0 = blockIdx.x << 7;

  f32x4 acc[4][4] = {};

  const int i0 = t, i1 = t + 256;
  const int ar0 = i0 >> 2, as0 = (i0 & 3) ^ (ar0 & 3);
  const int ar1 = i1 >> 2, as1 = (i1 & 3) ^ (ar1 & 3);
  const unsigned short* ga0 = A + (long)(m0 + ar0) * 1024 + as0 * 8;
  const unsigned short* ga1 = A + (long)(m0 + ar1) * 1024 + as1 * 8;
  const unsigned short* gb0 = W + (long)(n0 + ar0) * 1024 + as0 * 8;
  const unsigned short* gb1 = W + (long)(n0 + ar1) * 1024 + as1 * 8;
  const int lo0 = i0 * 16, lo1 = i1 * 16;

  int aoff[4], boff[4];
#pragma unroll
  for (int i = 0; i < 4; i++) {
    const int ra = (wr << 6) + (i << 4) + c;
    aoff[i] = ra * 64 + ((g << 4) ^ ((ra & 3) << 4));
    const int rb = (wc << 6) + (i << 4) + c;
    boff[i] = rb * 64 + ((g << 4) ^ ((rb & 3) << 4));
  }

  gload16(ga0, lds_a[0] + lo0);
  gload16(ga1, lds_a[0] + lo1);
  gload16(gb0, lds_b[0] + lo0);
  gload16(gb1, lds_b[0] + lo1);

  for (int kt = 0; kt < 32; kt++) {
    const int cur = kt & 1;
    VMCNT0();
    __builtin_amdgcn_s_barrier();
    if (kt + 1 < 32) {
      gload16(ga0 + ((kt + 1) << 5), lds_a[cur ^ 1] + lo0);
      gload16(ga1 + ((kt + 1) << 5), lds_a[cur ^ 1] + lo1);
      gload16(gb0 + ((kt + 1) << 5), lds_b[cur ^ 1] + lo0);
      gload16(gb1 + ((kt + 1) << 5), lds_b[cur ^ 1] + lo1);
    }
    u32x4 af[4], bf[4];
#pragma unroll
    for (int i = 0; i < 4; i++) af[i] = *(const u32x4*)(lds_a[cur] + aoff[i]);
#pragma unroll
    for (int j = 0; j < 4; j++) bf[j] = *(const u32x4*)(lds_b[cur] + boff[j]);
#pragma unroll
    for (int i = 0; i < 4; i++)
#pragma unroll
      for (int j = 0; j < 4; j++)
        mfma16(acc[i][j], af[i], bf[j]);
  }

  NOPG(acc[0][0], acc[0][1], acc[0][2], acc[0][3]);
  NOPG(acc[1][0], acc[1][1], acc[1][2], acc[1][3]);
  NOPG(acc[2][0], acc[2][1], acc[2][2], acc[2][3]);
  NOPG(acc[3][0], acc[3][1], acc[3][2], acc[3][3]);

  if (mode == 1) {
#pragma unroll
    for (int j = 0; j < 4; j++) {
      const int n = n0 + (wc << 6) + (j << 4) + c;
      const float bb = bias[n];
      const int h = n >> 6, d = n & 63;
#pragma unroll
      for (int i = 0; i < 4; i++) {
        const int m = m0 + (wr << 6) + (i << 4) + (g << 2);
        const int b = m >> 11, s = m & 2047;
        ushort4 o;
        o.x = f2h(acc[i][j][0] + bb);
        o.y = f2h(acc[i][j][1] + bb);
        o.z = f2h(acc[i][j][2] + bb);
        o.w = f2h(acc[i][j][3] + bb);
        *(ushort4*)&((unsigned short*)out)[((long)((b << 4) + h) * 64 + d) * 2048 + s] = o;
      }
    }
  } else {
#pragma unroll
    for (int j = 0; j < 4; j++) {
      const int n = n0 + (wc << 6) + (j << 4) + c;
      const float bb = bias[n];
#pragma unroll
      for (int i = 0; i < 4; i++) {
#pragma unroll
        for (int r = 0; r < 4; r++) {
          const int m = m0 + (wr << 6) + (i << 4) + (g << 2) + r;
          const float val = (acc[i][j][r] + bb) * oscale;
          if (mode == 2) {
            ((float*)out)[(long)m * 1024 + n] = val;
          } else {
            const int b = m >> 11, s = m & 2047;
            const int h = n >> 6, d = n & 63;
            ((unsigned short*)out)[((long)((b << 4) + h) * 2048 + s) * 64 + d] = f2h(val);
          }
        }
      }
    }
  }
}

__global__ __launch_bounds__(256) void gemm_proj(
    const unsigned short* kb, const unsigned short* qb, const unsigned short* vb,
    const unsigned short* wkb, const unsigned short* wqb, const unsigned short* wvb,
    const float* bk, const float* bq, const float* bvv,
    unsigned short* Kp, unsigned short* Qp, unsigned short* VpT) {
  const int z = blockIdx.z;
  const unsigned short* A = (z == 0) ? kb : (z == 1) ? qb : vb;
  const unsigned short* W = (z == 0) ? wkb : (z == 1) ? wqb : wvb;
  const float* bias = (z == 0) ? bk : (z == 1) ? bq : bvv;
  void* out = (z == 0) ? (void*)Kp : (z == 1) ? (void*)Qp : (void*)VpT;
  const float sc = (z == 1) ? 11.5415603271f : 1.0f;   // 8*log2(e) folded into Q
  gemm_body(A, W, bias, out, (z == 2) ? 1 : 0, sc);
}

__global__ __launch_bounds__(256) void gemm_out(
    const unsigned short* A, const unsigned short* W, const float* bias, float* out) {
  gemm_body(A, W, bias, out, 2, 1.0f);
}

// ---------------- flash attention, swapped-operand 32x32x16 ------------------
// Grid (bh=32, rank=32), qt = 31-rank (LPT). Block = 128 thr = 2 waves, BOTH
// waves own the same 64-row q-tile: wave w covers rows qt*64 + w*32 ..+32.
// Both iterate kv tiles 0..qt (identical) sharing staged K/V -> no idle slots.
// MFMA C layout (m74/m101): col=lane&31, row=(r&3)+8*(r>>2)+4*(lane>>5).
__global__ __launch_bounds__(128) void attn_kernel(
    const unsigned short* __restrict__ Qp, const unsigned short* __restrict__ Kp,
    const unsigned short* __restrict__ VpT, unsigned short* __restrict__ O) {
  __shared__ alignas(16) char lds_k[2][8192];  // K tile [64 kv][64 d], swizzled
  __shared__ alignas(16) char lds_v[2][8192];  // V^T tile [64 d][64 kv], swizzled

  const int t = threadIdx.x;
  const int lane = t & 63, w = t >> 6;
  const int hi = lane >> 5, c32 = lane & 31;
  const int bh = blockIdx.x;
  const int qt = 31 - (int)blockIdx.y;         // longest first (LPT)
  const int qs = (qt << 6) + (w << 5);         // wave w: 32 q-rows within the tile
  const int ntiles = qt + 1;

  // staging: each of 128 threads does 4 K-slots + 4 V-slots of 16B per tile
  const unsigned short* gk[4]; const unsigned short* gv[4]; int lofs[4];
#pragma unroll
  for (int n = 0; n < 4; n++) {
    const int idx = t + 128 * n;
    const int row = idx >> 3, sl = (idx & 7) ^ (row & 7);
    gk[n] = Kp + ((long)bh * 2048 + row) * 64 + sl * 8;
    gv[n] = VpT + ((long)bh * 64 + row) * 2048 + sl * 8;
    lofs[n] = idx * 16;
  }

  // LDS read offsets: row = 32*x + c32, 16B slot = 2*y + hi, XOR-swizzled
  int koff[2][4];
#pragma unroll
  for (int x = 0; x < 2; x++)
#pragma unroll
    for (int y = 0; y < 4; y++) {
      const int row = 32 * x + c32;
      koff[x][y] = row * 128 + ((((y << 1) + hi) << 4) ^ ((row & 7) << 4));
    }

  // Q fragment (B-operand): lane holds Q[qs+c32][k = 16*ks + 8*hi + j]
  const unsigned short* qrow = Qp + ((long)bh * 2048 + qs + c32) * 64 + hi * 8;
  f16x8 qf[4];
#pragma unroll
  for (int ks = 0; ks < 4; ks++) qf[ks] = *(const f16x8*)(qrow + ks * 16);

  f32x16 oT0 = {}, oT1 = {};                   // O^T: d-tiles 0/1, col=q=c32
  float mrun = -1e30f, lrun = 0.f;
  const int qloc = (qs & 63) + c32;            // causal threshold on diag tile

  // prologue: stage tile 0 into buf 0
#pragma unroll
  for (int n = 0; n < 4; n++) {
    gload16(gk[n], lds_k[0] + lofs[n]);
    gload16(gv[n], lds_v[0] + lofs[n]);
  }

  for (int tt = 0; tt < ntiles; tt++) {
    const int cur = tt & 1;
    VMCNT0();                                  // buf[cur] loads landed
    __builtin_amdgcn_s_barrier();
    if (tt + 1 < ntiles) {
      const long kvn = (long)(tt + 1) << 6;
#pragma unroll
      for (int n = 0; n < 4; n++) {
        gload16(gk[n] + kvn * 64, lds_k[cur ^ 1] + lofs[n]);
        gload16(gv[n] + kvn,      lds_v[cur ^ 1] + lofs[n]);
      }
    }

    // ---- QK^T (swapped): S^T[kv][q], kv subtiles 0/1 --------------------
    f32x16 s0 = {}, s1 = {};
    __builtin_amdgcn_s_setprio(1);
#pragma unroll
    for (int ks = 0; ks < 4; ks++) {
      const f16x8 a0 = *(const f16x8*)(lds_k[cur] + koff[0][ks]);
      const f16x8 a1 = *(const f16x8*)(lds_k[cur] + koff[1][ks]);
      s0 = __builtin_amdgcn_mfma_f32_32x32x16_f16(a0, qf[ks], s0, 0, 0, 0);
      s1 = __builtin_amdgcn_mfma_f32_32x32x16_f16(a1, qf[ks], s1, 0, 0, 0);
    }
    __builtin_amdgcn_s_setprio(0);

    if (tt == qt) {                            // causal mask, diagonal tile only
#pragma unroll
      for (int r = 0; r < 16; r++) {
        const int kvc = (r & 3) + 8 * (r >> 2) + 4 * hi;
        if (kvc > qloc)      s0[r] = -1e30f;
        if (kvc + 32 > qloc) s1[r] = -1e30f;
      }
    }

    // ---- online softmax, lane-local (q = c32); tree reductions ----------
    float tm[16];
#pragma unroll
    for (int r = 0; r < 16; r++) tm[r] = fmaxf(s0[r], s1[r]);
#pragma unroll
    for (int d = 8; d >= 1; d >>= 1)
#pragma unroll
      for (int r = 0; r < 8; r++)
        if (r < d) tm[r] = fmaxf(tm[r], tm[r + d]);
    float x, y;
    swap_pair(tm[0], x, y);                    // {own, partner} halves
    const float pmax = fmaxf(x, y);            // true tile max for this q

    // defer-max: rescale only when the max actually grew past THR=8 (exp2 units)
    if (!__all(pmax - mrun <= 8.0f)) {
      const float mnew = fmaxf(mrun, pmax);
      const float corr = exp2f(mrun - mnew);
      mrun = mnew;
      lrun *= corr;
      oT0 *= corr;
      oT1 *= corr;
    }

#pragma unroll
    for (int r = 0; r < 16; r++) {
      s0[r] = exp2f(s0[r] - mrun);             // <= 2^8 when deferred
      s1[r] = exp2f(s1[r] - mrun);
    }
    float ts[16];
#pragma unroll
    for (int r = 0; r < 16; r++) ts[r] = s0[r] + s1[r];
#pragma unroll
    for (int d = 8; d >= 1; d >>= 1)
#pragma unroll
      for (int r = 0; r < 8; r++)
        if (r < d) ts[r] = ts[r] + ts[r + d];
    lrun += ts[0];

    // ---- pack P to fp16 + permlane into PV B-fragments ------------------
    unsigned pk[8];
#pragma unroll
    for (int m = 0; m < 8; m++) pk[m] = pkrtz(s0[2 * m], s0[2 * m + 1]);
    pswap(pk[0], pk[2]); pswap(pk[1], pk[3]);
    pswap(pk[4], pk[6]); pswap(pk[5], pk[7]);
    const f16x8 pf0 = mkfrag(pk[0], pk[1], pk[2], pk[3]);   // kv 0..15
    const f16x8 pf1 = mkfrag(pk[4], pk[5], pk[6], pk[7]);   // kv 16..31
#pragma unroll
    for (int m = 0; m < 8; m++) pk[m] = pkrtz(s1[2 * m], s1[2 * m + 1]);
    pswap(pk[0], pk[2]); pswap(pk[1], pk[3]);
    pswap(pk[4], pk[6]); pswap(pk[5], pk[7]);
    const f16x8 pf2 = mkfrag(pk[0], pk[1], pk[2], pk[3]);   // kv 32..47
    const f16x8 pf3 = mkfrag(pk[4], pk[5], pk[6], pk[7]);   // kv 48..63

    // ---- PV: O^T[d][q] += V^T * P --------------------------------------
    __builtin_amdgcn_s_setprio(1);
    {
      const f16x8 v00 = *(const f16x8*)(lds_v[cur] + koff[0][0]);
      const f16x8 v01 = *(const f16x8*)(lds_v[cur] + koff[0][1]);
      const f16x8 v02 = *(const f16x8*)(lds_v[cur] + koff[0][2]);
      const f16x8 v03 = *(const f16x8*)(lds_v[cur] + koff[0][3]);
      oT0 = __builtin_amdgcn_mfma_f32_32x32x16_f16(v00, pf0, oT0, 0, 0, 0);
      oT0 = __builtin_amdgcn_mfma_f32_32x32x16_f16(v01, pf1, oT0, 0, 0, 0);
      oT0 = __builtin_amdgcn_mfma_f32_32x32x16_f16(v02, pf2, oT0, 0, 0, 0);
      oT0 = __builtin_amdgcn_mfma_f32_32x32x16_f16(v03, pf3, oT0, 0, 0, 0);
      const f16x8 v10 = *(const f16x8*)(lds_v[cur] + koff[1][0]);
      const f16x8 v11 = *(const f16x8*)(lds_v[cur] + koff[1][1]);
      const f16x8 v12 = *(const f16x8*)(lds_v[cur] + koff[1][2]);
      const f16x8 v13 = *(const f16x8*)(lds_v[cur] + koff[1][3]);
      oT1 = __builtin_amdgcn_mfma_f32_32x32x16_f16(v10, pf0, oT1, 0, 0, 0);
      oT1 = __builtin_amdgcn_mfma_f32_32x32x16_f16(v11, pf1, oT1, 0, 0, 0);
      oT1 = __builtin_amdgcn_mfma_f32_32x32x16_f16(v12, pf2, oT1, 0, 0, 0);
      oT1 = __builtin_amdgcn_mfma_f32_32x32x16_f16(v13, pf3, oT1, 0, 0, 0);
    }
    __builtin_amdgcn_s_setprio(0);
  }

  // ---- epilogue: combine denom across lane pair, write O ----------------
  float sx, sy;
  swap_pair(lrun, sx, sy);
  const float inv = 1.0f / (sx + sy);
  const int b = bh >> 4, h = bh & 15;
  const long rowbase = ((long)b * 2048 + qs + c32) * 1024 + (h << 6);
#pragma unroll
  for (int dt = 0; dt < 2; dt++) {
#pragma unroll
    for (int g4 = 0; g4 < 4; g4++) {
      const f32x16& o = dt ? oT1 : oT0;
      uint2 pkd;
      pkd.x = pkrtz(o[4 * g4 + 0] * inv, o[4 * g4 + 1] * inv);
      pkd.y = pkrtz(o[4 * g4 + 2] * inv, o[4 * g4 + 3] * inv);
      *(uint2*)&O[rowbase + 32 * dt + 8 * g4 + 4 * hi] = pkd;
    }
  }
}

// ---------------- launch ------------------------------------------------------
extern "C" void kernel_launch(void* const* d_in, const int* in_sizes, int n_in,
                              void* d_out, int out_size, void* d_ws, size_t ws_size,
                              hipStream_t stream) {
  (void)in_sizes; (void)n_in; (void)out_size; (void)ws_size;
  const float* kin = (const float*)d_in[0];
  const float* qin = (const float*)d_in[1];
  const float* vin = (const float*)d_in[2];
  const float* wk  = (const float*)d_in[4];
  const float* bk  = (const float*)d_in[5];
  const float* wq  = (const float*)d_in[6];
  const float* bq  = (const float*)d_in[7];
  const float* wv  = (const float*)d_in[8];
  const float* bv  = (const float*)d_in[9];
  const float* wo  = (const float*)d_in[10];
  const float* bo  = (const float*)d_in[11];

  unsigned short* ws  = (unsigned short*)d_ws;
  unsigned short* kb  = ws;
  unsigned short* qb  = ws + 4194304;
  unsigned short* vb  = ws + 8388608;
  unsigned short* wkb = ws + 12582912;
  unsigned short* wqb = ws + 13631488;
  unsigned short* wvb = ws + 14680064;
  unsigned short* wob = ws + 15728640;
  unsigned short* Kp  = ws + 16777216;            // [B,H,S,64]
  unsigned short* Qp  = ws + 20971520;            // [B,H,S,64], pre-scaled 8*log2e
  unsigned short* VpT = ws + 25165824;            // [B,H,64,S]
  unsigned short* Oo  = ws + 29360128;            // [B,S,D] fp16

  cvt_all<<<16384, 256, 0, stream>>>(kin, qin, vin, wk, wq, wv, wo, ws);
  gemm_proj<<<dim3(8, 32, 3), 256, 0, stream>>>(kb, qb, vb, wkb, wqb, wvb,
                                                bk, bq, bv, Kp, Qp, VpT);
  attn_kernel<<<dim3(32, 32), 128, 0, stream>>>(Qp, Kp, VpT, Oo);
  gemm_out<<<dim3(8, 32), 256, 0, stream>>>(Oo, wob, bo, (float*)d_out);
}

// Round 11
// 130.495 us; speedup vs baseline: 1.1068x; 1.1068x over previous
//
#include <hip/hip_runtime.h>

// MHA fused forward: B=2,S=2048,D=1024,H=16,DK=64, causal, scores *= 8.
// Pipeline: cvt(fp32->fp16) -> 3x proj GEMM (fused, grid.z) -> flash attn -> out GEMM.
// Attn: 32x32x16 MFMA, swapped QK^T (S^T = K*Q^T), softmax in-register via
// permlane32_swap builtin, P packed (cvt_pkrtz+permlane) into PV B-fragment,
// O^T = V^T*P with lane-local rescale.
// R11: exp2f() lowers to __ocml_exp2_f32 (~20+ insts, no fast-math) and we issue
// 32/tile/wave -> the hidden ~1500 cyc/iter VALU load that kept attn at ~70us
// across three structural rewrites. Use __builtin_amdgcn_exp2f (1x v_exp_f32).

typedef float f32x4 __attribute__((ext_vector_type(4)));
typedef float f32x16 __attribute__((ext_vector_type(16)));
typedef unsigned int u32x4 __attribute__((ext_vector_type(4)));
typedef _Float16 f16x8 __attribute__((ext_vector_type(8)));
typedef __fp16 fp16x2 __attribute__((ext_vector_type(2)));

#define DEV static __device__ __forceinline__

DEV unsigned short f2h(float x) {
  _Float16 h = (_Float16)x;
  union { _Float16 h; unsigned short u; } v; v.h = h;
  return v.u;
}

DEV unsigned pkrtz(float a, float b) {
  union { fp16x2 h; unsigned u; } v;
  v.h = __builtin_amdgcn_cvt_pkrtz(a, b);
  return v.u;
}

DEV float fexp2(float x) { return __builtin_amdgcn_exp2f(x); }  // raw v_exp_f32

// permlane32_swap builtin: lanes 0-31 of b' get a's lanes 32-63 and vice versa.
DEV void pswap(unsigned& a, unsigned& b) {
  auto r = __builtin_amdgcn_permlane32_swap(a, b, false, false);
  a = r[0]; b = r[1];
}

// Give every lane the {own, partner(lane^32)} pair of v in (x, y).
DEV void swap_pair(float v, float& x, float& y) {
  union { float f; unsigned u; } in; in.f = v;
  auto r = __builtin_amdgcn_permlane32_swap(in.u, in.u, false, false);
  union { unsigned u; float f; } ox, oy; ox.u = r[0]; oy.u = r[1];
  x = ox.f; y = oy.f;
}

DEV f16x8 mkfrag(unsigned a, unsigned b, unsigned c, unsigned d) {
  union { unsigned u[4]; f16x8 v; } z;
  z.u[0] = a; z.u[1] = b; z.u[2] = c; z.u[3] = d;
  return z.v;
}

DEV void mfma16(f32x4& d, u32x4 a, u32x4 b) {
  asm("v_mfma_f32_16x16x32_f16 %0, %1, %2, %0" : "+v"(d) : "v"(a), "v"(b));
}

DEV void gload16(const void* g, void* l) {
  __builtin_amdgcn_global_load_lds(
      (const __attribute__((address_space(1))) unsigned int*)g,
      (__attribute__((address_space(3))) unsigned int*)l, 16, 0, 0);
}

#define VMCNT0() asm volatile("s_waitcnt vmcnt(0)" ::: "memory")
#define NOPG(a,b,c,d)  asm volatile("s_nop 7\n\ts_nop 7" : "+v"(a), "+v"(b), "+v"(c), "+v"(d))

// ---------------- fp32 -> fp16 convert (k,q,v,wk,wq,wv,wo), 16.78M elements ----
__global__ __launch_bounds__(256) void cvt_all(
    const float* __restrict__ k, const float* __restrict__ q, const float* __restrict__ v,
    const float* __restrict__ wk, const float* __restrict__ wq, const float* __restrict__ wv,
    const float* __restrict__ wo, unsigned short* __restrict__ dst) {
  const int i = (blockIdx.x * 256 + threadIdx.x) * 4;
  const float* src; int off;
  if (i < 4194304)       { src = k;  off = 0; }
  else if (i < 8388608)  { src = q;  off = 4194304; }
  else if (i < 12582912) { src = v;  off = 8388608; }
  else if (i < 13631488) { src = wk; off = 12582912; }
  else if (i < 14680064) { src = wq; off = 13631488; }
  else if (i < 15728640) { src = wv; off = 14680064; }
  else                   { src = wo; off = 15728640; }
  float4 val = *(const float4*)(src + (i - off));
  ushort4 o;
  o.x = f2h(val.x); o.y = f2h(val.y); o.z = f2h(val.z); o.w = f2h(val.w);
  *(ushort4*)(dst + i) = o;
}

// ---------------- NT GEMM 128x128 tile, BK=32, M=4096,N=1024,K=1024 -----------
DEV void gemm_body(const unsigned short* __restrict__ A, const unsigned short* __restrict__ W,
                   const float* __restrict__ bias, void* __restrict__ out, int mode,
                   float oscale) {
  __shared__ alignas(16) char lds_a[2][8192];
  __shared__ alignas(16) char lds_b[2][8192];
  const int t = threadIdx.x;
  const int l = t & 63, g = l >> 4, c = l & 15, w = t >> 6;
  const int wr = w >> 1, wc = w & 1;
  const int m0 = blockIdx.y << 7, n0 = blockIdx.x << 7;

  f32x4 acc[4][4] = {};

  const int i0 = t, i1 = t + 256;
  const int ar0 = i0 >> 2, as0 = (i0 & 3) ^ (ar0 & 3);
  const int ar1 = i1 >> 2, as1 = (i1 & 3) ^ (ar1 & 3);
  const unsigned short* ga0 = A + (long)(m0 + ar0) * 1024 + as0 * 8;
  const unsigned short* ga1 = A + (long)(m0 + ar1) * 1024 + as1 * 8;
  const unsigned short* gb0 = W + (long)(n0 + ar0) * 1024 + as0 * 8;
  const unsigned short* gb1 = W + (long)(n0 + ar1) * 1024 + as1 * 8;
  const int lo0 = i0 * 16, lo1 = i1 * 16;

  int aoff[4], boff[4];
#pragma unroll
  for (int i = 0; i < 4; i++) {
    const int ra = (wr << 6) + (i << 4) + c;
    aoff[i] = ra * 64 + ((g << 4) ^ ((ra & 3) << 4));
    const int rb = (wc << 6) + (i << 4) + c;
    boff[i] = rb * 64 + ((g << 4) ^ ((rb & 3) << 4));
  }

  gload16(ga0, lds_a[0] + lo0);
  gload16(ga1, lds_a[0] + lo1);
  gload16(gb0, lds_b[0] + lo0);
  gload16(gb1, lds_b[0] + lo1);

  for (int kt = 0; kt < 32; kt++) {
    const int cur = kt & 1;
    VMCNT0();
    __builtin_amdgcn_s_barrier();
    if (kt + 1 < 32) {
      gload16(ga0 + ((kt + 1) << 5), lds_a[cur ^ 1] + lo0);
      gload16(ga1 + ((kt + 1) << 5), lds_a[cur ^ 1] + lo1);
      gload16(gb0 + ((kt + 1) << 5), lds_b[cur ^ 1] + lo0);
      gload16(gb1 + ((kt + 1) << 5), lds_b[cur ^ 1] + lo1);
    }
    u32x4 af[4], bf[4];
#pragma unroll
    for (int i = 0; i < 4; i++) af[i] = *(const u32x4*)(lds_a[cur] + aoff[i]);
#pragma unroll
    for (int j = 0; j < 4; j++) bf[j] = *(const u32x4*)(lds_b[cur] + boff[j]);
#pragma unroll
    for (int i = 0; i < 4; i++)
#pragma unroll
      for (int j = 0; j < 4; j++)
        mfma16(acc[i][j], af[i], bf[j]);
  }

  NOPG(acc[0][0], acc[0][1], acc[0][2], acc[0][3]);
  NOPG(acc[1][0], acc[1][1], acc[1][2], acc[1][3]);
  NOPG(acc[2][0], acc[2][1], acc[2][2], acc[2][3]);
  NOPG(acc[3][0], acc[3][1], acc[3][2], acc[3][3]);

  if (mode == 1) {
#pragma unroll
    for (int j = 0; j < 4; j++) {
      const int n = n0 + (wc << 6) + (j << 4) + c;
      const float bb = bias[n];
      const int h = n >> 6, d = n & 63;
#pragma unroll
      for (int i = 0; i < 4; i++) {
        const int m = m0 + (wr << 6) + (i << 4) + (g << 2);
        const int b = m >> 11, s = m & 2047;
        ushort4 o;
        o.x = f2h(acc[i][j][0] + bb);
        o.y = f2h(acc[i][j][1] + bb);
        o.z = f2h(acc[i][j][2] + bb);
        o.w = f2h(acc[i][j][3] + bb);
        *(ushort4*)&((unsigned short*)out)[((long)((b << 4) + h) * 64 + d) * 2048 + s] = o;
      }
    }
  } else {
#pragma unroll
    for (int j = 0; j < 4; j++) {
      const int n = n0 + (wc << 6) + (j << 4) + c;
      const float bb = bias[n];
#pragma unroll
      for (int i = 0; i < 4; i++) {
#pragma unroll
        for (int r = 0; r < 4; r++) {
          const int m = m0 + (wr << 6) + (i << 4) + (g << 2) + r;
          const float val = (acc[i][j][r] + bb) * oscale;
          if (mode == 2) {
            ((float*)out)[(long)m * 1024 + n] = val;
          } else {
            const int b = m >> 11, s = m & 2047;
            const int h = n >> 6, d = n & 63;
            ((unsigned short*)out)[((long)((b << 4) + h) * 2048 + s) * 64 + d] = f2h(val);
          }
        }
      }
    }
  }
}

__global__ __launch_bounds__(256) void gemm_proj(
    const unsigned short* kb, const unsigned short* qb, const unsigned short* vb,
    const unsigned short* wkb, const unsigned short* wqb, const unsigned short* wvb,
    const float* bk, const float* bq, const float* bvv,
    unsigned short* Kp, unsigned short* Qp, unsigned short* VpT) {
  const int z = blockIdx.z;
  const unsigned short* A = (z == 0) ? kb : (z == 1) ? qb : vb;
  const unsigned short* W = (z == 0) ? wkb : (z == 1) ? wqb : wvb;
  const float* bias = (z == 0) ? bk : (z == 1) ? bq : bvv;
  void* out = (z == 0) ? (void*)Kp : (z == 1) ? (void*)Qp : (void*)VpT;
  const float sc = (z == 1) ? 11.5415603271f : 1.0f;   // 8*log2(e) folded into Q
  gemm_body(A, W, bias, out, (z == 2) ? 1 : 0, sc);
}

__global__ __launch_bounds__(256) void gemm_out(
    const unsigned short* A, const unsigned short* W, const float* bias, float* out) {
  gemm_body(A, W, bias, out, 2, 1.0f);
}

// ---------------- flash attention, swapped-operand 32x32x16 ------------------
// Grid (bh=32, rank=32), qt = 31-rank (LPT). Block = 128 thr = 2 waves, both
// waves own the same 64-row q-tile: wave w covers rows qt*64 + w*32 ..+32.
// MFMA C layout (m74/m101): col=lane&31, row=(r&3)+8*(r>>2)+4*(lane>>5).
__global__ __launch_bounds__(128) void attn_kernel(
    const unsigned short* __restrict__ Qp, const unsigned short* __restrict__ Kp,
    const unsigned short* __restrict__ VpT, unsigned short* __restrict__ O) {
  __shared__ alignas(16) char lds_k[2][8192];  // K tile [64 kv][64 d], swizzled
  __shared__ alignas(16) char lds_v[2][8192];  // V^T tile [64 d][64 kv], swizzled

  const int t = threadIdx.x;
  const int lane = t & 63, w = t >> 6;
  const int hi = lane >> 5, c32 = lane & 31;
  const int bh = blockIdx.x;
  const int qt = 31 - (int)blockIdx.y;         // longest first (LPT)
  const int qs = (qt << 6) + (w << 5);         // wave w: 32 q-rows within the tile
  const int ntiles = qt + 1;

  // staging: each of 128 threads does 4 K-slots + 4 V-slots of 16B per tile
  const unsigned short* gk[4]; const unsigned short* gv[4]; int lofs[4];
#pragma unroll
  for (int n = 0; n < 4; n++) {
    const int idx = t + 128 * n;
    const int row = idx >> 3, sl = (idx & 7) ^ (row & 7);
    gk[n] = Kp + ((long)bh * 2048 + row) * 64 + sl * 8;
    gv[n] = VpT + ((long)bh * 64 + row) * 2048 + sl * 8;
    lofs[n] = idx * 16;
  }

  // LDS read offsets: row = 32*x + c32, 16B slot = 2*y + hi, XOR-swizzled
  int koff[2][4];
#pragma unroll
  for (int x = 0; x < 2; x++)
#pragma unroll
    for (int y = 0; y < 4; y++) {
      const int row = 32 * x + c32;
      koff[x][y] = row * 128 + ((((y << 1) + hi) << 4) ^ ((row & 7) << 4));
    }

  // Q fragment (B-operand): lane holds Q[qs+c32][k = 16*ks + 8*hi + j]
  const unsigned short* qrow = Qp + ((long)bh * 2048 + qs + c32) * 64 + hi * 8;
  f16x8 qf[4];
#pragma unroll
  for (int ks = 0; ks < 4; ks++) qf[ks] = *(const f16x8*)(qrow + ks * 16);

  f32x16 oT0 = {}, oT1 = {};                   // O^T: d-tiles 0/1, col=q=c32
  float mrun = -1e30f, lrun = 0.f;
  const int qloc = (qs & 63) + c32;            // causal threshold on diag tile

  // prologue: stage tile 0 into buf 0
#pragma unroll
  for (int n = 0; n < 4; n++) {
    gload16(gk[n], lds_k[0] + lofs[n]);
    gload16(gv[n], lds_v[0] + lofs[n]);
  }

  for (int tt = 0; tt < ntiles; tt++) {
    const int cur = tt & 1;
    VMCNT0();                                  // buf[cur] loads landed
    __builtin_amdgcn_s_barrier();
    if (tt + 1 < ntiles) {
      const long kvn = (long)(tt + 1) << 6;
#pragma unroll
      for (int n = 0; n < 4; n++) {
        gload16(gk[n] + kvn * 64, lds_k[cur ^ 1] + lofs[n]);
        gload16(gv[n] + kvn,      lds_v[cur ^ 1] + lofs[n]);
      }
    }

    // ---- QK^T (swapped): S^T[kv][q], kv subtiles 0/1 --------------------
    f32x16 s0 = {}, s1 = {};
    __builtin_amdgcn_s_setprio(1);
#pragma unroll
    for (int ks = 0; ks < 4; ks++) {
      const f16x8 a0 = *(const f16x8*)(lds_k[cur] + koff[0][ks]);
      const f16x8 a1 = *(const f16x8*)(lds_k[cur] + koff[1][ks]);
      s0 = __builtin_amdgcn_mfma_f32_32x32x16_f16(a0, qf[ks], s0, 0, 0, 0);
      s1 = __builtin_amdgcn_mfma_f32_32x32x16_f16(a1, qf[ks], s1, 0, 0, 0);
    }
    __builtin_amdgcn_s_setprio(0);

    if (tt == qt) {                            // causal mask, diagonal tile only
#pragma unroll
      for (int r = 0; r < 16; r++) {
        const int kvc = (r & 3) + 8 * (r >> 2) + 4 * hi;
        if (kvc > qloc)      s0[r] = -1e30f;
        if (kvc + 32 > qloc) s1[r] = -1e30f;
      }
    }

    // ---- online softmax, lane-local (q = c32); tree reductions ----------
    float tm[16];
#pragma unroll
    for (int r = 0; r < 16; r++) tm[r] = fmaxf(s0[r], s1[r]);
#pragma unroll
    for (int d = 8; d >= 1; d >>= 1)
#pragma unroll
      for (int r = 0; r < 8; r++)
        if (r < d) tm[r] = fmaxf(tm[r], tm[r + d]);
    float x, y;
    swap_pair(tm[0], x, y);                    // {own, partner} halves
    const float pmax = fmaxf(x, y);            // true tile max for this q

    // defer-max: rescale only when the max actually grew past THR=8 (exp2 units)
    if (!__all(pmax - mrun <= 8.0f)) {
      const float mnew = fmaxf(mrun, pmax);
      const float corr = fexp2(mrun - mnew);
      mrun = mnew;
      lrun *= corr;
      oT0 *= corr;
      oT1 *= corr;
    }

#pragma unroll
    for (int r = 0; r < 16; r++) {
      s0[r] = fexp2(s0[r] - mrun);             // <= 2^8 when deferred
      s1[r] = fexp2(s1[r] - mrun);
    }
    float ts[16];
#pragma unroll
    for (int r = 0; r < 16; r++) ts[r] = s0[r] + s1[r];
#pragma unroll
    for (int d = 8; d >= 1; d >>= 1)
#pragma unroll
      for (int r = 0; r < 8; r++)
        if (r < d) ts[r] = ts[r] + ts[r + d];
    lrun += ts[0];

    // ---- pack P to fp16 + permlane into PV B-fragments ------------------
    unsigned pk[8];
#pragma unroll
    for (int m = 0; m < 8; m++) pk[m] = pkrtz(s0[2 * m], s0[2 * m + 1]);
    pswap(pk[0], pk[2]); pswap(pk[1], pk[3]);
    pswap(pk[4], pk[6]); pswap(pk[5], pk[7]);
    const f16x8 pf0 = mkfrag(pk[0], pk[1], pk[2], pk[3]);   // kv 0..15
    const f16x8 pf1 = mkfrag(pk[4], pk[5], pk[6], pk[7]);   // kv 16..31
#pragma unroll
    for (int m = 0; m < 8; m++) pk[m] = pkrtz(s1[2 * m], s1[2 * m + 1]);
    pswap(pk[0], pk[2]); pswap(pk[1], pk[3]);
    pswap(pk[4], pk[6]); pswap(pk[5], pk[7]);
    const f16x8 pf2 = mkfrag(pk[0], pk[1], pk[2], pk[3]);   // kv 32..47
    const f16x8 pf3 = mkfrag(pk[4], pk[5], pk[6], pk[7]);   // kv 48..63

    // ---- PV: O^T[d][q] += V^T * P --------------------------------------
    __builtin_amdgcn_s_setprio(1);
    {
      const f16x8 v00 = *(const f16x8*)(lds_v[cur] + koff[0][0]);
      const f16x8 v01 = *(const f16x8*)(lds_v[cur] + koff[0][1]);
      const f16x8 v02 = *(const f16x8*)(lds_v[cur] + koff[0][2]);
      const f16x8 v03 = *(const f16x8*)(lds_v[cur] + koff[0][3]);
      oT0 = __builtin_amdgcn_mfma_f32_32x32x16_f16(v00, pf0, oT0, 0, 0, 0);
      oT0 = __builtin_amdgcn_mfma_f32_32x32x16_f16(v01, pf1, oT0, 0, 0, 0);
      oT0 = __builtin_amdgcn_mfma_f32_32x32x16_f16(v02, pf2, oT0, 0, 0, 0);
      oT0 = __builtin_amdgcn_mfma_f32_32x32x16_f16(v03, pf3, oT0, 0, 0, 0);
      const f16x8 v10 = *(const f16x8*)(lds_v[cur] + koff[1][0]);
      const f16x8 v11 = *(const f16x8*)(lds_v[cur] + koff[1][1]);
      const f16x8 v12 = *(const f16x8*)(lds_v[cur] + koff[1][2]);
      const f16x8 v13 = *(const f16x8*)(lds_v[cur] + koff[1][3]);
      oT1 = __builtin_amdgcn_mfma_f32_32x32x16_f16(v10, pf0, oT1, 0, 0, 0);
      oT1 = __builtin_amdgcn_mfma_f32_32x32x16_f16(v11, pf1, oT1, 0, 0, 0);
      oT1 = __builtin_amdgcn_mfma_f32_32x32x16_f16(v12, pf2, oT1, 0, 0, 0);
      oT1 = __builtin_amdgcn_mfma_f32_32x32x16_f16(v13, pf3, oT1, 0, 0, 0);
    }
    __builtin_amdgcn_s_setprio(0);
  }

  // ---- epilogue: combine denom across lane pair, write O ----------------
  float sx, sy;
  swap_pair(lrun, sx, sy);
  const float inv = 1.0f / (sx + sy);
  const int b = bh >> 4, h = bh & 15;
  const long rowbase = ((long)b * 2048 + qs + c32) * 1024 + (h << 6);
#pragma unroll
  for (int dt = 0; dt < 2; dt++) {
#pragma unroll
    for (int g4 = 0; g4 < 4; g4++) {
      const f32x16& o = dt ? oT1 : oT0;
      uint2 pkd;
      pkd.x = pkrtz(o[4 * g4 + 0] * inv, o[4 * g4 + 1] * inv);
      pkd.y = pkrtz(o[4 * g4 + 2] * inv, o[4 * g4 + 3] * inv);
      *(uint2*)&O[rowbase + 32 * dt + 8 * g4 + 4 * hi] = pkd;
    }
  }
}

// ---------------- launch ------------------------------------------------------
extern "C" void kernel_launch(void* const* d_in, const int* in_sizes, int n_in,
                              void* d_out, int out_size, void* d_ws, size_t ws_size,
                              hipStream_t stream) {
  (void)in_sizes; (void)n_in; (void)out_size; (void)ws_size;
  const float* kin = (const float*)d_in[0];
  const float* qin = (const float*)d_in[1];
  const float* vin = (const float*)d_in[2];
  const float* wk  = (const float*)d_in[4];
  const float* bk  = (const float*)d_in[5];
  const float* wq  = (const float*)d_in[6];
  const float* bq  = (const float*)d_in[7];
  const float* wv  = (const float*)d_in[8];
  const float* bv  = (const float*)d_in[9];
  const float* wo  = (const float*)d_in[10];
  const float* bo  = (const float*)d_in[11];

  unsigned short* ws  = (unsigned short*)d_ws;
  unsigned short* kb  = ws;
  unsigned short* qb  = ws + 4194304;
  unsigned short* vb  = ws + 8388608;
  unsigned short* wkb = ws + 12582912;
  unsigned short* wqb = ws + 13631488;
  unsigned short* wvb = ws + 14680064;
  unsigned short* wob = ws + 15728640;
  unsigned short* Kp  = ws + 16777216;            // [B,H,S,64]
  unsigned short* Qp  = ws + 20971520;            // [B,H,S,64], pre-scaled 8*log2e
  unsigned short* VpT = ws + 25165824;            // [B,H,64,S]
  unsigned short* Oo  = ws + 29360128;            // [B,S,D] fp16

  cvt_all<<<16384, 256, 0, stream>>>(kin, qin, vin, wk, wq, wv, wo, ws);
  gemm_proj<<<dim3(8, 32, 3), 256, 0, stream>>>(kb, qb, vb, wkb, wqb, wvb,
                                                bk, bq, bv, Kp, Qp, VpT);
  attn_kernel<<<dim3(32, 32), 128, 0, stream>>>(Qp, Kp, VpT, Oo);
  gemm_out<<<dim3(8, 32), 256, 0, stream>>>(Oo, wob, bo, (float*)d_out);
}